// Round 9
// baseline (275.253 us; speedup 1.0000x reference)
//
#include <hip/hip_runtime.h>
#include <hip/hip_bf16.h>

#define HID 128
#define NH  4          // heads
#define FEAT (NH*HID)  // 512 per node per projection
#define F2   (2*FEAT)  // xl|xr packed row stride = 1024
#define NEG_SLOPE 0.2f
#define BN_EPS 1e-5f

typedef __attribute__((ext_vector_type(8))) short bf16x8;   // 8 bf16 = 4 VGPR
typedef __attribute__((ext_vector_type(4))) float f32x4;

// ---------- helpers ----------
__device__ inline ushort f2bf(float f) {     // RNE f32 -> bf16
    unsigned u = __float_as_uint(f);
    return (ushort)((u + 0x7fffu + ((u >> 16) & 1u)) >> 16);
}
__device__ inline void ubf4(const ushort* p, float* o) {  // 4 bf16 -> 4 f32
    uint2 q = *(const uint2*)p;
    o[0] = __uint_as_float(q.x << 16); o[1] = __uint_as_float(q.x & 0xffff0000u);
    o[2] = __uint_as_float(q.y << 16); o[3] = __uint_as_float(q.y & 0xffff0000u);
}

// ---------- cast f32 -> bf16 (n % 4 == 0) + zero deg ----------
__global__ __launch_bounds__(256) void cast_bf16_deg(const float* __restrict__ in,
                                                     ushort* __restrict__ out, int n,
                                                     int* __restrict__ deg, int N)
{
    int gid = blockIdx.x * 256 + threadIdx.x;
    if (gid < N) deg[gid] = 0;
    int i = gid * 4;
    if (i >= n) return;
    float4 v = *(const float4*)(in + i);
    ushort4 o = make_ushort4(f2bf(v.x), f2bf(v.y), f2bf(v.z), f2bf(v.w));
    *(ushort4*)(out + i) = o;
}

// ---------- transpose + cast two K x Nc f32 mats -> [Nc][K] bf16 each ----------
__global__ __launch_bounds__(256) void transpose_cast2(const float* __restrict__ in0,
                                                       const float* __restrict__ in1,
                                                       ushort* __restrict__ out0,
                                                       ushort* __restrict__ out1,
                                                       int K, int Nc)
{
    const float* in  = blockIdx.z ? in1 : in0;
    ushort*      out = blockIdx.z ? out1 : out0;
    __shared__ float t[32][33];
    int bk = blockIdx.x * 32, bc = blockIdx.y * 32;
    int r = threadIdx.x >> 3, c4 = (threadIdx.x & 7) * 4;
    float4 v = *(const float4*)(in + (size_t)(bk + r) * Nc + bc + c4);
    t[r][c4 + 0] = v.x; t[r][c4 + 1] = v.y; t[r][c4 + 2] = v.z; t[r][c4 + 3] = v.w;
    __syncthreads();
    ushort4 o;
    o.x = f2bf(t[c4 + 0][r]); o.y = f2bf(t[c4 + 1][r]);
    o.z = f2bf(t[c4 + 2][r]); o.w = f2bf(t[c4 + 3][r]);
    *(ushort4*)(out + (size_t)(bc + r) * K + bk + c4) = o;
}

// ---------- bf16 MFMA GEMM: C[M][Nc] = A[M][K] @ Bt[Nc][K]^T ----------
// 128x128 tile, BK=32, 256 threads = 4 waves (2x2), per wave 4x4 frags 16x16.
__global__ __launch_bounds__(256) void gemm_bf16(const ushort* __restrict__ A,
                                                 const ushort* __restrict__ Bt,
                                                 ushort* __restrict__ C,
                                                 int M, int Nc, int K)
{
    __shared__ __align__(16) ushort As[128 * 40];  // row stride 40 (pad 8)
    __shared__ __align__(16) ushort Bs[128 * 40];
    const int bm = blockIdx.x * 128;
    const int bn = blockIdx.y * 128;
    const int tid = threadIdx.x;
    const int wid = tid >> 6, lane = tid & 63;
    const int wr = wid >> 1, wc = wid & 1;
    const int l15 = lane & 15, l4 = lane >> 4;

    f32x4 acc[4][4] = {};

    for (int k0 = 0; k0 < K; k0 += 32) {
        #pragma unroll
        for (int s = 0; s < 2; ++s) {               // A,B: 512 chunks of 16B each
            int c = tid + s * 256;
            int r = c >> 2, cc = (c & 3) * 8;
            uint4 v = make_uint4(0, 0, 0, 0);
            int gr = bm + r;
            if (gr < M) v = *(const uint4*)(A + (size_t)gr * K + k0 + cc);
            *(uint4*)&As[r * 40 + cc] = v;
            uint4 w = *(const uint4*)(Bt + (size_t)(bn + r) * K + k0 + cc);
            *(uint4*)&Bs[r * 40 + cc] = w;
        }
        __syncthreads();
        bf16x8 bfr[4];
        #pragma unroll
        for (int n = 0; n < 4; ++n)
            bfr[n] = *(const bf16x8*)&Bs[(wc * 64 + n * 16 + l15) * 40 + l4 * 8];
        #pragma unroll
        for (int m = 0; m < 4; ++m) {
            bf16x8 afr = *(const bf16x8*)&As[(wr * 64 + m * 16 + l15) * 40 + l4 * 8];
            #pragma unroll
            for (int n = 0; n < 4; ++n)
                acc[m][n] = __builtin_amdgcn_mfma_f32_16x16x32_bf16(afr, bfr[n], acc[m][n], 0, 0, 0);
        }
        __syncthreads();
    }
    #pragma unroll
    for (int m = 0; m < 4; ++m)
        #pragma unroll
        for (int n = 0; n < 4; ++n)
            #pragma unroll
            for (int r = 0; r < 4; ++r) {
                int row = bm + wr * 64 + m * 16 + l4 * 4 + r;
                int col = bn + wc * 64 + n * 16 + l15;
                if (row < M) C[(size_t)row * Nc + col] = f2bf(acc[m][n][r]);
            }
}

// ---------- CSR build ----------
__global__ __launch_bounds__(256) void csr_count(const int* __restrict__ ei,
                                                 int* __restrict__ deg,
                                                 int E, int Etot)
{
    int i = blockIdx.x * 256 + threadIdx.x;
    if (i >= Etot) return;
    int dst = (i < E) ? ei[E + i] : (i - E);
    atomicAdd(&deg[dst], 1);
}

__global__ __launch_bounds__(1024) void scan_rowptr(const int* __restrict__ deg,
                                                    int* __restrict__ rowptr,
                                                    int* __restrict__ cursor,
                                                    int N)
{
    __shared__ int part[1024];
    int t = threadIdx.x;
    int chunk = (N + 1023) / 1024;
    int lo = t * chunk;
    int hi = lo + chunk; if (hi > N) hi = N; if (lo > N) lo = N;
    int s = 0;
    for (int i = lo; i < hi; ++i) s += deg[i];
    part[t] = s;
    __syncthreads();
    for (int off = 1; off < 1024; off <<= 1) {
        int v = (t >= off) ? part[t - off] : 0;
        __syncthreads();
        part[t] += v;
        __syncthreads();
    }
    int base = (t == 0) ? 0 : part[t - 1];
    for (int i = lo; i < hi; ++i) {
        rowptr[i] = base;
        cursor[i] = base;
        base += deg[i];
    }
    if (t == 1023) rowptr[N] = part[1023];
}

__global__ __launch_bounds__(256) void csr_fill(const int* __restrict__ ei,
                                                int* __restrict__ cursor,
                                                int* __restrict__ csr_src,
                                                int* __restrict__ csr_eid,
                                                int E, int Etot)
{
    int i = blockIdx.x * 256 + threadIdx.x;
    if (i >= Etot) return;
    int src, dst;
    if (i < E) { src = ei[i]; dst = ei[E + i]; }
    else       { src = dst = i - E; }
    int pos = atomicAdd(&cursor[dst], 1);
    csr_src[pos] = src;
    csr_eid[pos] = i;
}

// ---------- fused attention: 2 nodes per block, 2 waves per node, 2 heads per wave ----------
// Within a wave: half = lane>>5 selects head (wave owns heads {2w, 2w+1});
// 32 lanes per head, 4 channels = 8B per lane. Full edge list scanned per wave.
// Head-mean combined via 4KB LDS; alpha finalized in-kernel; FINAL fuses the
// linear+relu+sigmoid head.
template <bool FINAL>
__global__ __launch_bounds__(256) void fused_attn(const ushort* __restrict__ xlxr,
                                                  const int* __restrict__ rowptr,
                                                  const int* __restrict__ csr_src,
                                                  const int* __restrict__ csr_eid,
                                                  const float* __restrict__ att,
                                                  float* __restrict__ alpha,
                                                  const float* __restrict__ bias,
                                                  const float* __restrict__ g,
                                                  const float* __restrict__ be,
                                                  const float* __restrict__ bmn,
                                                  const float* __restrict__ bvr,
                                                  ushort* __restrict__ hout,
                                                  const float* __restrict__ Wlin,
                                                  const float* __restrict__ blin,
                                                  float* __restrict__ out, int N)
{
    __shared__ float hs[2][NH][HID];   // [node_in_blk][head][ch]
    __shared__ float fin[4];
    const int tid = threadIdx.x;
    const int wid = tid >> 6;
    const int lane = tid & 63;
    const int nib = wid >> 1;                 // node in block
    const int n = blockIdx.x * 2 + nib;
    const int half = lane >> 5;
    const int head = (wid & 1) * 2 + half;
    const int cl = lane & 31;                 // channel lane within head
    const bool valid = n < N;
    const size_t foff = (size_t)head * HID + cl * 4;

    float xrv[4] = {}, atv[4] = {};
    if (valid) {
        ubf4(xlxr + (size_t)n * F2 + FEAT + foff, xrv);
        float4 a = *(const float4*)(att + foff);
        atv[0] = a.x; atv[1] = a.y; atv[2] = a.z; atv[3] = a.w;
    }

    float mrun = -1e30f, den = 0.f, acc[4] = {};
    const int beg = valid ? rowptr[n] : 0;
    const int end = valid ? rowptr[n + 1] : 0;
    int k = beg;

    for (; k + 3 < end; k += 4) {
        int s0 = csr_src[k],     s1 = csr_src[k + 1];
        int s2 = csr_src[k + 2], s3 = csr_src[k + 3];
        int e0 = csr_eid[k],     e1 = csr_eid[k + 1];
        int e2 = csr_eid[k + 2], e3 = csr_eid[k + 3];

        float xv0[4], xv1[4], xv2[4], xv3[4];
        ubf4(xlxr + (size_t)s0 * F2 + foff, xv0);
        ubf4(xlxr + (size_t)s1 * F2 + foff, xv1);
        ubf4(xlxr + (size_t)s2 * F2 + foff, xv2);
        ubf4(xlxr + (size_t)s3 * F2 + foff, xv3);

        float l0 = 0.f, l1 = 0.f, l2 = 0.f, l3 = 0.f;
        #pragma unroll
        for (int j = 0; j < 4; ++j) {
            float t0 = xv0[j] + xrv[j]; t0 = fmaxf(t0, NEG_SLOPE * t0);
            float t1 = xv1[j] + xrv[j]; t1 = fmaxf(t1, NEG_SLOPE * t1);
            float t2 = xv2[j] + xrv[j]; t2 = fmaxf(t2, NEG_SLOPE * t2);
            float t3 = xv3[j] + xrv[j]; t3 = fmaxf(t3, NEG_SLOPE * t3);
            l0 += t0 * atv[j]; l1 += t1 * atv[j];
            l2 += t2 * atv[j]; l3 += t3 * atv[j];
        }
        #pragma unroll
        for (int off = 1; off < 32; off <<= 1) {
            l0 += __shfl_xor(l0, off, 64);
            l1 += __shfl_xor(l1, off, 64);
            l2 += __shfl_xor(l2, off, 64);
            l3 += __shfl_xor(l3, off, 64);
        }
        if (cl == 0) {
            alpha[(size_t)e0 * NH + head] = l0;
            alpha[(size_t)e1 * NH + head] = l1;
            alpha[(size_t)e2 * NH + head] = l2;
            alpha[(size_t)e3 * NH + head] = l3;
        }
        float bmax = fmaxf(fmaxf(l0, l1), fmaxf(l2, l3));
        if (bmax > mrun) {
            float sc = __expf(mrun - bmax);
            den *= sc;
            #pragma unroll
            for (int j = 0; j < 4; ++j) acc[j] *= sc;
            mrun = bmax;
        }
        float w0 = __expf(l0 - mrun), w1 = __expf(l1 - mrun);
        float w2 = __expf(l2 - mrun), w3 = __expf(l3 - mrun);
        den += (w0 + w1) + (w2 + w3);
        #pragma unroll
        for (int j = 0; j < 4; ++j)
            acc[j] += (w0 * xv0[j] + w1 * xv1[j]) + (w2 * xv2[j] + w3 * xv3[j]);
    }

    for (; k < end; ++k) {
        int src = csr_src[k];
        int eid = csr_eid[k];
        float xv[4];
        ubf4(xlxr + (size_t)src * F2 + foff, xv);
        float s = 0.f;
        #pragma unroll
        for (int j = 0; j < 4; ++j) {
            float t = xv[j] + xrv[j];
            t = fmaxf(t, NEG_SLOPE * t);
            s += t * atv[j];
        }
        #pragma unroll
        for (int off = 1; off < 32; off <<= 1) s += __shfl_xor(s, off, 64);
        if (cl == 0) alpha[(size_t)eid * NH + head] = s;
        if (s > mrun) {
            float sc = __expf(mrun - s);
            den *= sc;
            #pragma unroll
            for (int j = 0; j < 4; ++j) acc[j] *= sc;
            mrun = s;
        }
        float e = __expf(s - mrun);
        den += e;
        #pragma unroll
        for (int j = 0; j < 4; ++j) acc[j] += e * xv[j];
    }

    float inv = 1.f / (den + 1e-16f);

    // stash per-head weighted means, combine across the node's 2 waves
    *(float4*)&hs[nib][head][cl * 4] =
        make_float4(acc[0] * inv, acc[1] * inv, acc[2] * inv, acc[3] * inv);
    __syncthreads();

    {
        const int cnib = tid >> 7;            // node index for combine phase
        const int c = tid & 127;
        const int n2 = blockIdx.x * 2 + cnib;
        if (n2 < N) {
            float s = (hs[cnib][0][c] + hs[cnib][1][c] +
                       hs[cnib][2][c] + hs[cnib][3][c]) * 0.25f + bias[c];
            float bn = (s - bmn[c]) * rsqrtf(bvr[c] + BN_EPS) * g[c] + be[c];
            float o = fmaxf(bn, 0.f);
            if (FINAL) {
                float p = o * Wlin[c];
                #pragma unroll
                for (int off = 1; off < 64; off <<= 1) p += __shfl_xor(p, off, 64);
                if (lane == 0) fin[wid] = p;
            } else {
                hout[(size_t)n2 * HID + c] = f2bf(o);
            }
        } else if (FINAL && lane == 0) {
            fin[wid] = 0.f;
        }
    }
    if (FINAL) {
        __syncthreads();
        if ((tid & 127) == 0 && n < N) {
            float z = fin[nib * 2] + fin[nib * 2 + 1] + blin[0];
            z = fmaxf(z, 0.f);
            out[n] = 1.f / (1.f + __expf(-z));
        }
    }

    // in-kernel alpha finalize: each 32-lane head-group rewrites its own raw logits
    asm volatile("s_waitcnt vmcnt(0)" ::: "memory");
    for (int k2 = beg + cl; k2 < end; k2 += 32) {
        size_t idx = (size_t)csr_eid[k2] * NH + head;
        alpha[idx] = __expf(alpha[idx] - mrun) * inv;
    }
}

extern "C" void kernel_launch(void* const* d_in, const int* in_sizes, int n_in,
                              void* d_out, int out_size, void* d_ws, size_t ws_size,
                              hipStream_t stream)
{
    const float* x    = (const float*)d_in[0];
    const int*   ei   = (const int*)d_in[1];
    const float* Wl1  = (const float*)d_in[2];
    const float* Wr1  = (const float*)d_in[3];
    const float* att1 = (const float*)d_in[4];
    const float* b1   = (const float*)d_in[5];
    const float* Wl2  = (const float*)d_in[6];
    const float* Wr2  = (const float*)d_in[7];
    const float* att2 = (const float*)d_in[8];
    const float* b2   = (const float*)d_in[9];
    const float* g1   = (const float*)d_in[10];
    const float* be1  = (const float*)d_in[11];
    const float* m1   = (const float*)d_in[12];
    const float* v1   = (const float*)d_in[13];
    const float* g2   = (const float*)d_in[14];
    const float* be2  = (const float*)d_in[15];
    const float* m2   = (const float*)d_in[16];
    const float* v2   = (const float*)d_in[17];
    const float* Wlin = (const float*)d_in[18];
    const float* blin = (const float*)d_in[19];

    const int IN_C = 256;
    const int N = in_sizes[0] / IN_C;       // 10000
    const int E = in_sizes[1] / 2;          // 320000
    const int Etot = E + N;                 // with self loops

    float* out    = (float*)d_out;          // [N]
    float* alpha1 = out + N;                // [Etot*NH]
    float* alpha2 = alpha1 + (size_t)Etot * NH;

    // workspace layout (bytes)
    char* wsb = (char*)d_ws;
    ushort* xbf   = (ushort*)wsb;                       wsb += (size_t)N * IN_C * 2;
    ushort* xlxr  = (ushort*)wsb;                       wsb += (size_t)N * F2 * 2;
    ushort* hbbf  = (ushort*)wsb;                       wsb += (size_t)N * HID * 2;
    ushort* wt1   = (ushort*)wsb;                       wsb += (size_t)F2 * IN_C * 2;  // [1024][256]
    ushort* wt2   = (ushort*)wsb;                       wsb += (size_t)F2 * HID * 2;   // [1024][128]
    int*    deg    = (int*)wsb;                         wsb += (size_t)N * 4;
    int*    cursor = (int*)wsb;                         wsb += (size_t)N * 4;
    int*    rowptr = (int*)wsb;                         wsb += (size_t)(N + 1) * 4;
    int*    csrsrc = (int*)wsb;                         wsb += (size_t)Etot * 4;
    int*    csreid = (int*)wsb;

    dim3 blk(256);
    dim3 gemm_grid((N + 127) / 128, F2 / 128);
    int attn_blocks = (N + 1) / 2;
    int etot_blocks = (Etot + 255) / 256;

    // ---- casts (+deg zero) ----
    cast_bf16_deg<<<(N * IN_C / 4 + 255) / 256, blk, 0, stream>>>(x, xbf, N * IN_C, deg, N);
    transpose_cast2<<<dim3(IN_C / 32, FEAT / 32, 2), blk, 0, stream>>>(Wl1, Wr1, wt1, wt1 + (size_t)FEAT * IN_C, IN_C, FEAT);
    transpose_cast2<<<dim3(HID / 32, FEAT / 32, 2), blk, 0, stream>>>(Wl2, Wr2, wt2, wt2 + (size_t)FEAT * HID, HID, FEAT);

    // ---- CSR build (shared by both layers) ----
    csr_count<<<etot_blocks, blk, 0, stream>>>(ei, deg, E, Etot);
    scan_rowptr<<<1, 1024, 0, stream>>>(deg, rowptr, cursor, N);
    csr_fill<<<etot_blocks, blk, 0, stream>>>(ei, cursor, csrsrc, csreid, E, Etot);

    // ================= layer 1 =================
    gemm_bf16<<<gemm_grid, blk, 0, stream>>>(xbf, wt1, xlxr, N, F2, IN_C);
    fused_attn<false><<<attn_blocks, blk, 0, stream>>>(xlxr, rowptr, csrsrc, csreid,
                                                       att1, alpha1, b1, g1, be1, m1, v1,
                                                       hbbf, Wlin, blin, out, N);

    // ================= layer 2 =================
    gemm_bf16<<<gemm_grid, blk, 0, stream>>>(hbbf, wt2, xlxr, N, F2, HID);
    fused_attn<true><<<attn_blocks, blk, 0, stream>>>(xlxr, rowptr, csrsrc, csreid,
                                                      att2, alpha2, b2, g2, be2, m2, v2,
                                                      hbbf, Wlin, blin, out, N);
}

// Round 10
// 250.251 us; speedup vs baseline: 1.0999x; 1.0999x over previous
//
#include <hip/hip_runtime.h>
#include <hip/hip_bf16.h>

#define HID 128
#define NH  4          // heads
#define FEAT (NH*HID)  // 512 per node per projection
#define F2   (2*FEAT)  // xl|xr packed row stride = 1024
#define NEG_SLOPE 0.2f
#define BN_EPS 1e-5f

typedef __attribute__((ext_vector_type(8))) short bf16x8;   // 8 bf16 = 4 VGPR
typedef __attribute__((ext_vector_type(4))) float f32x4;

// ---------- helpers ----------
__device__ inline ushort f2bf(float f) {     // RNE f32 -> bf16
    unsigned u = __float_as_uint(f);
    return (ushort)((u + 0x7fffu + ((u >> 16) & 1u)) >> 16);
}
__device__ inline void ubf8(const ushort* p, float* o) {  // 8 bf16 -> 8 f32
    uint4 q = *(const uint4*)p;
    o[0] = __uint_as_float(q.x << 16); o[1] = __uint_as_float(q.x & 0xffff0000u);
    o[2] = __uint_as_float(q.y << 16); o[3] = __uint_as_float(q.y & 0xffff0000u);
    o[4] = __uint_as_float(q.z << 16); o[5] = __uint_as_float(q.z & 0xffff0000u);
    o[6] = __uint_as_float(q.w << 16); o[7] = __uint_as_float(q.w & 0xffff0000u);
}

// ---------- cast f32 -> bf16 (n % 4 == 0) + zero deg ----------
__global__ __launch_bounds__(256) void cast_bf16_deg(const float* __restrict__ in,
                                                     ushort* __restrict__ out, int n,
                                                     int* __restrict__ deg, int N)
{
    int gid = blockIdx.x * 256 + threadIdx.x;
    if (gid < N) deg[gid] = 0;
    int i = gid * 4;
    if (i >= n) return;
    float4 v = *(const float4*)(in + i);
    ushort4 o = make_ushort4(f2bf(v.x), f2bf(v.y), f2bf(v.z), f2bf(v.w));
    *(ushort4*)(out + i) = o;
}

// ---------- transpose + cast two K x Nc f32 mats -> [Nc][K] bf16 each ----------
__global__ __launch_bounds__(256) void transpose_cast2(const float* __restrict__ in0,
                                                       const float* __restrict__ in1,
                                                       ushort* __restrict__ out0,
                                                       ushort* __restrict__ out1,
                                                       int K, int Nc)
{
    const float* in  = blockIdx.z ? in1 : in0;
    ushort*      out = blockIdx.z ? out1 : out0;
    __shared__ float t[32][33];
    int bk = blockIdx.x * 32, bc = blockIdx.y * 32;
    int r = threadIdx.x >> 3, c4 = (threadIdx.x & 7) * 4;
    float4 v = *(const float4*)(in + (size_t)(bk + r) * Nc + bc + c4);
    t[r][c4 + 0] = v.x; t[r][c4 + 1] = v.y; t[r][c4 + 2] = v.z; t[r][c4 + 3] = v.w;
    __syncthreads();
    ushort4 o;
    o.x = f2bf(t[c4 + 0][r]); o.y = f2bf(t[c4 + 1][r]);
    o.z = f2bf(t[c4 + 2][r]); o.w = f2bf(t[c4 + 3][r]);
    *(ushort4*)(out + (size_t)(bc + r) * K + bk + c4) = o;
}

// ---------- bf16 MFMA GEMM: C[M][Nc] = A[M][K] @ Bt[Nc][K]^T ----------
// 128x128 tile, BK=32, 256 threads = 4 waves (2x2), per wave 4x4 frags 16x16.
__global__ __launch_bounds__(256) void gemm_bf16(const ushort* __restrict__ A,
                                                 const ushort* __restrict__ Bt,
                                                 ushort* __restrict__ C,
                                                 int M, int Nc, int K)
{
    __shared__ __align__(16) ushort As[128 * 40];  // row stride 40 (pad 8)
    __shared__ __align__(16) ushort Bs[128 * 40];
    const int bm = blockIdx.x * 128;
    const int bn = blockIdx.y * 128;
    const int tid = threadIdx.x;
    const int wid = tid >> 6, lane = tid & 63;
    const int wr = wid >> 1, wc = wid & 1;
    const int l15 = lane & 15, l4 = lane >> 4;

    f32x4 acc[4][4] = {};

    for (int k0 = 0; k0 < K; k0 += 32) {
        #pragma unroll
        for (int s = 0; s < 2; ++s) {               // A,B: 512 chunks of 16B each
            int c = tid + s * 256;
            int r = c >> 2, cc = (c & 3) * 8;
            uint4 v = make_uint4(0, 0, 0, 0);
            int gr = bm + r;
            if (gr < M) v = *(const uint4*)(A + (size_t)gr * K + k0 + cc);
            *(uint4*)&As[r * 40 + cc] = v;
            uint4 w = *(const uint4*)(Bt + (size_t)(bn + r) * K + k0 + cc);
            *(uint4*)&Bs[r * 40 + cc] = w;
        }
        __syncthreads();
        bf16x8 bfr[4];
        #pragma unroll
        for (int n = 0; n < 4; ++n)
            bfr[n] = *(const bf16x8*)&Bs[(wc * 64 + n * 16 + l15) * 40 + l4 * 8];
        #pragma unroll
        for (int m = 0; m < 4; ++m) {
            bf16x8 afr = *(const bf16x8*)&As[(wr * 64 + m * 16 + l15) * 40 + l4 * 8];
            #pragma unroll
            for (int n = 0; n < 4; ++n)
                acc[m][n] = __builtin_amdgcn_mfma_f32_16x16x32_bf16(afr, bfr[n], acc[m][n], 0, 0, 0);
        }
        __syncthreads();
    }
    #pragma unroll
    for (int m = 0; m < 4; ++m)
        #pragma unroll
        for (int n = 0; n < 4; ++n)
            #pragma unroll
            for (int r = 0; r < 4; ++r) {
                int row = bm + wr * 64 + m * 16 + l4 * 4 + r;
                int col = bn + wc * 64 + n * 16 + l15;
                if (row < M) C[(size_t)row * Nc + col] = f2bf(acc[m][n][r]);
            }
}

// ---------- CSR build ----------
__global__ __launch_bounds__(256) void csr_count(const int* __restrict__ ei,
                                                 int* __restrict__ deg,
                                                 int E, int Etot)
{
    int i = blockIdx.x * 256 + threadIdx.x;
    if (i >= Etot) return;
    int dst = (i < E) ? ei[E + i] : (i - E);
    atomicAdd(&deg[dst], 1);
}

__global__ __launch_bounds__(1024) void scan_rowptr(const int* __restrict__ deg,
                                                    int* __restrict__ rowptr,
                                                    int* __restrict__ cursor,
                                                    int N)
{
    __shared__ int part[1024];
    int t = threadIdx.x;
    int chunk = (N + 1023) / 1024;
    int lo = t * chunk;
    int hi = lo + chunk; if (hi > N) hi = N; if (lo > N) lo = N;
    int s = 0;
    for (int i = lo; i < hi; ++i) s += deg[i];
    part[t] = s;
    __syncthreads();
    for (int off = 1; off < 1024; off <<= 1) {
        int v = (t >= off) ? part[t - off] : 0;
        __syncthreads();
        part[t] += v;
        __syncthreads();
    }
    int base = (t == 0) ? 0 : part[t - 1];
    for (int i = lo; i < hi; ++i) {
        rowptr[i] = base;
        cursor[i] = base;
        base += deg[i];
    }
    if (t == 1023) rowptr[N] = part[1023];
}

__global__ __launch_bounds__(256) void csr_fill(const int* __restrict__ ei,
                                                int* __restrict__ cursor,
                                                int* __restrict__ csr_src,
                                                int* __restrict__ csr_eid,
                                                int E, int Etot)
{
    int i = blockIdx.x * 256 + threadIdx.x;
    if (i >= Etot) return;
    int src, dst;
    if (i < E) { src = ei[i]; dst = ei[E + i]; }
    else       { src = dst = i - E; }
    int pos = atomicAdd(&cursor[dst], 1);
    csr_src[pos] = src;
    csr_eid[pos] = i;
}

// ---------- fused per-dst attention (R5/R8 geometry, unroll-8 pipelined) ----------
// One wave per node; head = lane>>4, sub = lane&15 covers 8 channels (16B/lane).
// xlxr rows are [xl(512) | xr(512)] packed, stride 1024.
// Unroll-8: all 8 index loads + 8 gathers issued before any compute (MLP depth 8).
// FINAL=false: write h (bf16). FINAL=true: fuse h@Wlin+blin -> relu -> sigmoid.
template <bool FINAL>
__global__ __launch_bounds__(256) void fused_attn(const ushort* __restrict__ xlxr,
                                                  const int* __restrict__ rowptr,
                                                  const int* __restrict__ csr_src,
                                                  const int* __restrict__ csr_eid,
                                                  const float* __restrict__ att,
                                                  float* __restrict__ alpha,
                                                  const float* __restrict__ bias,
                                                  const float* __restrict__ g,
                                                  const float* __restrict__ be,
                                                  const float* __restrict__ bmn,
                                                  const float* __restrict__ bvr,
                                                  ushort* __restrict__ hout,
                                                  const float* __restrict__ Wlin,
                                                  const float* __restrict__ blin,
                                                  float* __restrict__ out, int N)
{
    int n = (blockIdx.x * 256 + threadIdx.x) >> 6;
    int lane = threadIdx.x & 63;
    if (n >= N) return;
    int head = lane >> 4, sub = lane & 15;
    const size_t foff = (size_t)head * HID + sub * 8;

    float xrv[8], atv[8];
    ubf8(xlxr + (size_t)n * F2 + FEAT + foff, xrv);
    {
        const float4* a4 = (const float4*)(att + foff);
        float4 t0 = a4[0], t1 = a4[1];
        atv[0]=t0.x; atv[1]=t0.y; atv[2]=t0.z; atv[3]=t0.w;
        atv[4]=t1.x; atv[5]=t1.y; atv[6]=t1.z; atv[7]=t1.w;
    }

    float mrun = -1e30f, den = 0.f, acc[8] = {};
    const int beg = rowptr[n], end = rowptr[n + 1];
    int k = beg;

    // ---- unroll-8 main loop: 8 gathers in flight before any compute ----
    for (; k + 7 < end; k += 8) {
        int ss[8], ee[8];
        #pragma unroll
        for (int u = 0; u < 8; ++u) { ss[u] = csr_src[k + u]; ee[u] = csr_eid[k + u]; }

        float xv[8][8];
        #pragma unroll
        for (int u = 0; u < 8; ++u)
            ubf8(xlxr + (size_t)ss[u] * F2 + foff, xv[u]);

        float l[8];
        #pragma unroll
        for (int u = 0; u < 8; ++u) {
            float s = 0.f;
            #pragma unroll
            for (int j = 0; j < 8; ++j) {
                float t = xv[u][j] + xrv[j];
                t = fmaxf(t, NEG_SLOPE * t);
                s += t * atv[j];
            }
            l[u] = s;
        }
        #pragma unroll
        for (int off = 1; off < 16; off <<= 1) {
            #pragma unroll
            for (int u = 0; u < 8; ++u) l[u] += __shfl_xor(l[u], off, 64);
        }
        if (sub == 0) {
            #pragma unroll
            for (int u = 0; u < 8; ++u)
                alpha[(size_t)ee[u] * NH + head] = l[u];
        }
        float bmax = fmaxf(fmaxf(fmaxf(l[0], l[1]), fmaxf(l[2], l[3])),
                           fmaxf(fmaxf(l[4], l[5]), fmaxf(l[6], l[7])));
        if (bmax > mrun) {
            float sc = __expf(mrun - bmax);
            den *= sc;
            #pragma unroll
            for (int j = 0; j < 8; ++j) acc[j] *= sc;
            mrun = bmax;
        }
        float w[8];
        #pragma unroll
        for (int u = 0; u < 8; ++u) w[u] = __expf(l[u] - mrun);
        den += ((w[0] + w[1]) + (w[2] + w[3])) + ((w[4] + w[5]) + (w[6] + w[7]));
        #pragma unroll
        for (int j = 0; j < 8; ++j) {
            float a0 = (w[0] * xv[0][j] + w[1] * xv[1][j]) + (w[2] * xv[2][j] + w[3] * xv[3][j]);
            float a1 = (w[4] * xv[4][j] + w[5] * xv[5][j]) + (w[6] * xv[6][j] + w[7] * xv[7][j]);
            acc[j] += a0 + a1;
        }
    }

    // ---- remainder (<8 edges) ----
    for (; k < end; ++k) {
        int src = csr_src[k];
        int eid = csr_eid[k];
        float xv[8];
        ubf8(xlxr + (size_t)src * F2 + foff, xv);
        float s = 0.f;
        #pragma unroll
        for (int j = 0; j < 8; ++j) {
            float t = xv[j] + xrv[j];
            t = fmaxf(t, NEG_SLOPE * t);
            s += t * atv[j];
        }
        #pragma unroll
        for (int off = 1; off < 16; off <<= 1) s += __shfl_xor(s, off, 64);
        if (sub == 0) alpha[(size_t)eid * NH + head] = s;
        if (s > mrun) {
            float sc = __expf(mrun - s);
            den *= sc;
            #pragma unroll
            for (int j = 0; j < 8; ++j) acc[j] *= sc;
            mrun = s;
        }
        float e = __expf(s - mrun);
        den += e;
        #pragma unroll
        for (int j = 0; j < 8; ++j) acc[j] += e * xv[j];
    }

    float inv = 1.f / (den + 1e-16f);

    // head-mean via cross-head shuffles
    float t8[8];
    #pragma unroll
    for (int j = 0; j < 8; ++j) {
        float t = acc[j] * inv;
        t += __shfl_xor(t, 16, 64);
        t += __shfl_xor(t, 32, 64);
        t8[j] = t;
    }
    if (head == 0) {
        float o[8];
        #pragma unroll
        for (int j = 0; j < 8; ++j) {
            int c = sub * 8 + j;
            float s = t8[j] * 0.25f + bias[c];
            float bn = (s - bmn[c]) * rsqrtf(bvr[c] + BN_EPS) * g[c] + be[c];
            o[j] = fmaxf(bn, 0.f);
        }
        if (FINAL) {
            float p = 0.f;
            #pragma unroll
            for (int j = 0; j < 8; ++j) p += o[j] * Wlin[sub * 8 + j];
            p += __shfl_xor(p, 1, 64);
            p += __shfl_xor(p, 2, 64);
            p += __shfl_xor(p, 4, 64);
            p += __shfl_xor(p, 8, 64);
            if (sub == 0) {
                float z = fmaxf(p + blin[0], 0.f);
                out[n] = 1.f / (1.f + __expf(-z));
            }
        } else {
            uint4 ov;
            unsigned w[4];
            #pragma unroll
            for (int q = 0; q < 4; ++q)
                w[q] = (unsigned)f2bf(o[2 * q]) | ((unsigned)f2bf(o[2 * q + 1]) << 16);
            ov.x = w[0]; ov.y = w[1]; ov.z = w[2]; ov.w = w[3];
            *(uint4*)(hout + (size_t)n * HID + sub * 8) = ov;
        }
    }

    // in-kernel alpha finalize: each head-group rewrites its own raw logits
    asm volatile("s_waitcnt vmcnt(0)" ::: "memory");
    for (int k2 = beg + sub; k2 < end; k2 += 16) {
        size_t idx = (size_t)csr_eid[k2] * NH + head;
        alpha[idx] = __expf(alpha[idx] - mrun) * inv;
    }
}

extern "C" void kernel_launch(void* const* d_in, const int* in_sizes, int n_in,
                              void* d_out, int out_size, void* d_ws, size_t ws_size,
                              hipStream_t stream)
{
    const float* x    = (const float*)d_in[0];
    const int*   ei   = (const int*)d_in[1];
    const float* Wl1  = (const float*)d_in[2];
    const float* Wr1  = (const float*)d_in[3];
    const float* att1 = (const float*)d_in[4];
    const float* b1   = (const float*)d_in[5];
    const float* Wl2  = (const float*)d_in[6];
    const float* Wr2  = (const float*)d_in[7];
    const float* att2 = (const float*)d_in[8];
    const float* b2   = (const float*)d_in[9];
    const float* g1   = (const float*)d_in[10];
    const float* be1  = (const float*)d_in[11];
    const float* m1   = (const float*)d_in[12];
    const float* v1   = (const float*)d_in[13];
    const float* g2   = (const float*)d_in[14];
    const float* be2  = (const float*)d_in[15];
    const float* m2   = (const float*)d_in[16];
    const float* v2   = (const float*)d_in[17];
    const float* Wlin = (const float*)d_in[18];
    const float* blin = (const float*)d_in[19];

    const int IN_C = 256;
    const int N = in_sizes[0] / IN_C;       // 10000
    const int E = in_sizes[1] / 2;          // 320000
    const int Etot = E + N;                 // with self loops

    float* out    = (float*)d_out;          // [N]
    float* alpha1 = out + N;                // [Etot*NH]
    float* alpha2 = alpha1 + (size_t)Etot * NH;

    // workspace layout (bytes)
    char* wsb = (char*)d_ws;
    ushort* xbf   = (ushort*)wsb;                       wsb += (size_t)N * IN_C * 2;
    ushort* xlxr  = (ushort*)wsb;                       wsb += (size_t)N * F2 * 2;
    ushort* hbbf  = (ushort*)wsb;                       wsb += (size_t)N * HID * 2;
    ushort* wt1   = (ushort*)wsb;                       wsb += (size_t)F2 * IN_C * 2;  // [1024][256]
    ushort* wt2   = (ushort*)wsb;                       wsb += (size_t)F2 * HID * 2;   // [1024][128]
    int*    deg    = (int*)wsb;                         wsb += (size_t)N * 4;
    int*    cursor = (int*)wsb;                         wsb += (size_t)N * 4;
    int*    rowptr = (int*)wsb;                         wsb += (size_t)(N + 1) * 4;
    int*    csrsrc = (int*)wsb;                         wsb += (size_t)Etot * 4;
    int*    csreid = (int*)wsb;

    dim3 blk(256);
    dim3 gemm_grid((N + 127) / 128, F2 / 128);
    int node_wave_blocks = (N + 3) / 4;
    int etot_blocks = (Etot + 255) / 256;

    // ---- casts (+deg zero) ----
    cast_bf16_deg<<<(N * IN_C / 4 + 255) / 256, blk, 0, stream>>>(x, xbf, N * IN_C, deg, N);
    transpose_cast2<<<dim3(IN_C / 32, FEAT / 32, 2), blk, 0, stream>>>(Wl1, Wr1, wt1, wt1 + (size_t)FEAT * IN_C, IN_C, FEAT);
    transpose_cast2<<<dim3(HID / 32, FEAT / 32, 2), blk, 0, stream>>>(Wl2, Wr2, wt2, wt2 + (size_t)FEAT * HID, HID, FEAT);

    // ---- CSR build (shared by both layers) ----
    csr_count<<<etot_blocks, blk, 0, stream>>>(ei, deg, E, Etot);
    scan_rowptr<<<1, 1024, 0, stream>>>(deg, rowptr, cursor, N);
    csr_fill<<<etot_blocks, blk, 0, stream>>>(ei, cursor, csrsrc, csreid, E, Etot);

    // ================= layer 1 =================
    gemm_bf16<<<gemm_grid, blk, 0, stream>>>(xbf, wt1, xlxr, N, F2, IN_C);
    fused_attn<false><<<node_wave_blocks, blk, 0, stream>>>(xlxr, rowptr, csrsrc, csreid,
                                                            att1, alpha1, b1, g1, be1, m1, v1,
                                                            hbbf, Wlin, blin, out, N);

    // ================= layer 2 =================
    gemm_bf16<<<gemm_grid, blk, 0, stream>>>(hbbf, wt2, xlxr, N, F2, HID);
    fused_attn<true><<<node_wave_blocks, blk, 0, stream>>>(xlxr, rowptr, csrsrc, csreid,
                                                           att2, alpha2, b2, g2, be2, m2, v2,
                                                           hbbf, Wlin, blin, out, N);
}

// Round 11
// 211.925 us; speedup vs baseline: 1.2988x; 1.1808x over previous
//
#include <hip/hip_runtime.h>
#include <hip/hip_bf16.h>

#define HID 128
#define NH  4          // heads
#define FEAT (NH*HID)  // 512 per node per projection
#define F2   (2*FEAT)  // xl|xr packed row stride = 1024
#define NEG_SLOPE 0.2f
#define BN_EPS 1e-5f
#define CAP  128       // max buffered edges per node (deg ~ Poisson(32); fallback if exceeded)

typedef __attribute__((ext_vector_type(8))) short bf16x8;   // 8 bf16 = 4 VGPR
typedef __attribute__((ext_vector_type(4))) float f32x4;

// ---------- helpers ----------
__device__ inline ushort f2bf(float f) {     // RNE f32 -> bf16
    unsigned u = __float_as_uint(f);
    return (ushort)((u + 0x7fffu + ((u >> 16) & 1u)) >> 16);
}
__device__ inline void ubf8(const ushort* p, float* o) {  // 8 bf16 -> 8 f32
    uint4 q = *(const uint4*)p;
    o[0] = __uint_as_float(q.x << 16); o[1] = __uint_as_float(q.x & 0xffff0000u);
    o[2] = __uint_as_float(q.y << 16); o[3] = __uint_as_float(q.y & 0xffff0000u);
    o[4] = __uint_as_float(q.z << 16); o[5] = __uint_as_float(q.z & 0xffff0000u);
    o[6] = __uint_as_float(q.w << 16); o[7] = __uint_as_float(q.w & 0xffff0000u);
}

// ---------- cast f32 -> bf16 (n % 4 == 0) + zero deg ----------
__global__ __launch_bounds__(256) void cast_bf16_deg(const float* __restrict__ in,
                                                     ushort* __restrict__ out, int n,
                                                     int* __restrict__ deg, int N)
{
    int gid = blockIdx.x * 256 + threadIdx.x;
    if (gid < N) deg[gid] = 0;
    int i = gid * 4;
    if (i >= n) return;
    float4 v = *(const float4*)(in + i);
    ushort4 o = make_ushort4(f2bf(v.x), f2bf(v.y), f2bf(v.z), f2bf(v.w));
    *(ushort4*)(out + i) = o;
}

// ---------- transpose + cast two K x Nc f32 mats -> [Nc][K] bf16 each ----------
__global__ __launch_bounds__(256) void transpose_cast2(const float* __restrict__ in0,
                                                       const float* __restrict__ in1,
                                                       ushort* __restrict__ out0,
                                                       ushort* __restrict__ out1,
                                                       int K, int Nc)
{
    const float* in  = blockIdx.z ? in1 : in0;
    ushort*      out = blockIdx.z ? out1 : out0;
    __shared__ float t[32][33];
    int bk = blockIdx.x * 32, bc = blockIdx.y * 32;
    int r = threadIdx.x >> 3, c4 = (threadIdx.x & 7) * 4;
    float4 v = *(const float4*)(in + (size_t)(bk + r) * Nc + bc + c4);
    t[r][c4 + 0] = v.x; t[r][c4 + 1] = v.y; t[r][c4 + 2] = v.z; t[r][c4 + 3] = v.w;
    __syncthreads();
    ushort4 o;
    o.x = f2bf(t[c4 + 0][r]); o.y = f2bf(t[c4 + 1][r]);
    o.z = f2bf(t[c4 + 2][r]); o.w = f2bf(t[c4 + 3][r]);
    *(ushort4*)(out + (size_t)(bc + r) * K + bk + c4) = o;
}

// ---------- bf16 MFMA GEMM: C[M][Nc] = A[M][K] @ Bt[Nc][K]^T ----------
// 128x128 tile, BK=32, 256 threads = 4 waves (2x2), per wave 4x4 frags 16x16.
__global__ __launch_bounds__(256) void gemm_bf16(const ushort* __restrict__ A,
                                                 const ushort* __restrict__ Bt,
                                                 ushort* __restrict__ C,
                                                 int M, int Nc, int K)
{
    __shared__ __align__(16) ushort As[128 * 40];  // row stride 40 (pad 8)
    __shared__ __align__(16) ushort Bs[128 * 40];
    const int bm = blockIdx.x * 128;
    const int bn = blockIdx.y * 128;
    const int tid = threadIdx.x;
    const int wid = tid >> 6, lane = tid & 63;
    const int wr = wid >> 1, wc = wid & 1;
    const int l15 = lane & 15, l4 = lane >> 4;

    f32x4 acc[4][4] = {};

    for (int k0 = 0; k0 < K; k0 += 32) {
        #pragma unroll
        for (int s = 0; s < 2; ++s) {               // A,B: 512 chunks of 16B each
            int c = tid + s * 256;
            int r = c >> 2, cc = (c & 3) * 8;
            uint4 v = make_uint4(0, 0, 0, 0);
            int gr = bm + r;
            if (gr < M) v = *(const uint4*)(A + (size_t)gr * K + k0 + cc);
            *(uint4*)&As[r * 40 + cc] = v;
            uint4 w = *(const uint4*)(Bt + (size_t)(bn + r) * K + k0 + cc);
            *(uint4*)&Bs[r * 40 + cc] = w;
        }
        __syncthreads();
        bf16x8 bfr[4];
        #pragma unroll
        for (int n = 0; n < 4; ++n)
            bfr[n] = *(const bf16x8*)&Bs[(wc * 64 + n * 16 + l15) * 40 + l4 * 8];
        #pragma unroll
        for (int m = 0; m < 4; ++m) {
            bf16x8 afr = *(const bf16x8*)&As[(wr * 64 + m * 16 + l15) * 40 + l4 * 8];
            #pragma unroll
            for (int n = 0; n < 4; ++n)
                acc[m][n] = __builtin_amdgcn_mfma_f32_16x16x32_bf16(afr, bfr[n], acc[m][n], 0, 0, 0);
        }
        __syncthreads();
    }
    #pragma unroll
    for (int m = 0; m < 4; ++m)
        #pragma unroll
        for (int n = 0; n < 4; ++n)
            #pragma unroll
            for (int r = 0; r < 4; ++r) {
                int row = bm + wr * 64 + m * 16 + l4 * 4 + r;
                int col = bn + wc * 64 + n * 16 + l15;
                if (row < M) C[(size_t)row * Nc + col] = f2bf(acc[m][n][r]);
            }
}

// ---------- CSR build ----------
__global__ __launch_bounds__(256) void csr_count(const int* __restrict__ ei,
                                                 int* __restrict__ deg,
                                                 int E, int Etot)
{
    int i = blockIdx.x * 256 + threadIdx.x;
    if (i >= Etot) return;
    int dst = (i < E) ? ei[E + i] : (i - E);
    atomicAdd(&deg[dst], 1);
}

__global__ __launch_bounds__(1024) void scan_rowptr(const int* __restrict__ deg,
                                                    int* __restrict__ rowptr,
                                                    int* __restrict__ cursor,
                                                    int N)
{
    __shared__ int part[1024];
    int t = threadIdx.x;
    int chunk = (N + 1023) / 1024;
    int lo = t * chunk;
    int hi = lo + chunk; if (hi > N) hi = N; if (lo > N) lo = N;
    int s = 0;
    for (int i = lo; i < hi; ++i) s += deg[i];
    part[t] = s;
    __syncthreads();
    for (int off = 1; off < 1024; off <<= 1) {
        int v = (t >= off) ? part[t - off] : 0;
        __syncthreads();
        part[t] += v;
        __syncthreads();
    }
    int base = (t == 0) ? 0 : part[t - 1];
    for (int i = lo; i < hi; ++i) {
        rowptr[i] = base;
        cursor[i] = base;
        base += deg[i];
    }
    if (t == 1023) rowptr[N] = part[1023];
}

__global__ __launch_bounds__(256) void csr_fill(const int* __restrict__ ei,
                                                int* __restrict__ cursor,
                                                int* __restrict__ csr_src,
                                                int* __restrict__ csr_eid,
                                                int E, int Etot)
{
    int i = blockIdx.x * 256 + threadIdx.x;
    if (i >= Etot) return;
    int src, dst;
    if (i < E) { src = ei[i]; dst = ei[E + i]; }
    else       { src = dst = i - E; }
    int pos = atomicAdd(&cursor[dst], 1);
    csr_src[pos] = src;
    csr_eid[pos] = i;
}

// ---------- fused per-dst attention (R5/R8 geometry, unroll-4, LDS logit buffer) ----------
// One wave per node; head = lane>>4, sub = lane&15 covers 8 channels (16B/lane).
// Raw logits buffered in wave-local LDS (deg<=CAP, no barriers needed), alpha
// written ONCE finalized as float4. Fallback to global-raw path for deg>CAP.
// FINAL=false: write h (bf16). FINAL=true: fuse h@Wlin+blin -> relu -> sigmoid.
template <bool FINAL>
__global__ __launch_bounds__(256) void fused_attn(const ushort* __restrict__ xlxr,
                                                  const int* __restrict__ rowptr,
                                                  const int* __restrict__ csr_src,
                                                  const int* __restrict__ csr_eid,
                                                  const float* __restrict__ att,
                                                  float* __restrict__ alpha,
                                                  const float* __restrict__ bias,
                                                  const float* __restrict__ g,
                                                  const float* __restrict__ be,
                                                  const float* __restrict__ bmn,
                                                  const float* __restrict__ bvr,
                                                  ushort* __restrict__ hout,
                                                  const float* __restrict__ Wlin,
                                                  const float* __restrict__ blin,
                                                  float* __restrict__ out, int N)
{
    __shared__ __align__(16) float lraw[4][CAP][NH];   // 8 KB, wave-local
    int n = (blockIdx.x * 256 + threadIdx.x) >> 6;
    int lane = threadIdx.x & 63;
    if (n >= N) return;
    const int wid = (threadIdx.x >> 6);
    int head = lane >> 4, sub = lane & 15;
    const size_t foff = (size_t)head * HID + sub * 8;

    float xrv[8], atv[8];
    ubf8(xlxr + (size_t)n * F2 + FEAT + foff, xrv);
    {
        const float4* a4 = (const float4*)(att + foff);
        float4 t0 = a4[0], t1 = a4[1];
        atv[0]=t0.x; atv[1]=t0.y; atv[2]=t0.z; atv[3]=t0.w;
        atv[4]=t1.x; atv[5]=t1.y; atv[6]=t1.z; atv[7]=t1.w;
    }

    float mrun = -1e30f, den = 0.f, acc[8] = {};
    const int beg = rowptr[n], end = rowptr[n + 1];
    const int deg = end - beg;
    const bool big = deg > CAP;       // wave-uniform
    int k = beg;

    for (; k + 3 < end; k += 4) {
        int s0 = csr_src[k],     s1 = csr_src[k + 1];
        int s2 = csr_src[k + 2], s3 = csr_src[k + 3];

        float xv0[8], xv1[8], xv2[8], xv3[8];
        ubf8(xlxr + (size_t)s0 * F2 + foff, xv0);
        ubf8(xlxr + (size_t)s1 * F2 + foff, xv1);
        ubf8(xlxr + (size_t)s2 * F2 + foff, xv2);
        ubf8(xlxr + (size_t)s3 * F2 + foff, xv3);

        float l0 = 0.f, l1 = 0.f, l2 = 0.f, l3 = 0.f;
        #pragma unroll
        for (int j = 0; j < 8; ++j) {
            float t0 = xv0[j] + xrv[j]; t0 = fmaxf(t0, NEG_SLOPE * t0);
            float t1 = xv1[j] + xrv[j]; t1 = fmaxf(t1, NEG_SLOPE * t1);
            float t2 = xv2[j] + xrv[j]; t2 = fmaxf(t2, NEG_SLOPE * t2);
            float t3 = xv3[j] + xrv[j]; t3 = fmaxf(t3, NEG_SLOPE * t3);
            l0 += t0 * atv[j]; l1 += t1 * atv[j];
            l2 += t2 * atv[j]; l3 += t3 * atv[j];
        }
        #pragma unroll
        for (int off = 1; off < 16; off <<= 1) {
            l0 += __shfl_xor(l0, off, 64);
            l1 += __shfl_xor(l1, off, 64);
            l2 += __shfl_xor(l2, off, 64);
            l3 += __shfl_xor(l3, off, 64);
        }
        if (!big) {
            if (sub == 0) {
                int kk = k - beg;
                lraw[wid][kk + 0][head] = l0;
                lraw[wid][kk + 1][head] = l1;
                lraw[wid][kk + 2][head] = l2;
                lraw[wid][kk + 3][head] = l3;
            }
        } else if (sub == 0) {
            alpha[(size_t)csr_eid[k]     * NH + head] = l0;
            alpha[(size_t)csr_eid[k + 1] * NH + head] = l1;
            alpha[(size_t)csr_eid[k + 2] * NH + head] = l2;
            alpha[(size_t)csr_eid[k + 3] * NH + head] = l3;
        }
        float bmax = fmaxf(fmaxf(l0, l1), fmaxf(l2, l3));
        if (bmax > mrun) {
            float sc = __expf(mrun - bmax);
            den *= sc;
            #pragma unroll
            for (int j = 0; j < 8; ++j) acc[j] *= sc;
            mrun = bmax;
        }
        float w0 = __expf(l0 - mrun), w1 = __expf(l1 - mrun);
        float w2 = __expf(l2 - mrun), w3 = __expf(l3 - mrun);
        den += (w0 + w1) + (w2 + w3);
        #pragma unroll
        for (int j = 0; j < 8; ++j)
            acc[j] += (w0 * xv0[j] + w1 * xv1[j]) + (w2 * xv2[j] + w3 * xv3[j]);
    }

    for (; k < end; ++k) {
        int src = csr_src[k];
        float xv[8];
        ubf8(xlxr + (size_t)src * F2 + foff, xv);
        float s = 0.f;
        #pragma unroll
        for (int j = 0; j < 8; ++j) {
            float t = xv[j] + xrv[j];
            t = fmaxf(t, NEG_SLOPE * t);
            s += t * atv[j];
        }
        #pragma unroll
        for (int off = 1; off < 16; off <<= 1) s += __shfl_xor(s, off, 64);
        if (!big) {
            if (sub == 0) lraw[wid][k - beg][head] = s;
        } else if (sub == 0) {
            alpha[(size_t)csr_eid[k] * NH + head] = s;
        }
        if (s > mrun) {
            float sc = __expf(mrun - s);
            den *= sc;
            #pragma unroll
            for (int j = 0; j < 8; ++j) acc[j] *= sc;
            mrun = s;
        }
        float e = __expf(s - mrun);
        den += e;
        #pragma unroll
        for (int j = 0; j < 8; ++j) acc[j] += e * xv[j];
    }

    float inv = 1.f / (den + 1e-16f);

    // head-mean via cross-head shuffles
    float t8[8];
    #pragma unroll
    for (int j = 0; j < 8; ++j) {
        float t = acc[j] * inv;
        t += __shfl_xor(t, 16, 64);
        t += __shfl_xor(t, 32, 64);
        t8[j] = t;
    }
    if (head == 0) {
        float o[8];
        #pragma unroll
        for (int j = 0; j < 8; ++j) {
            int c = sub * 8 + j;
            float s = t8[j] * 0.25f + bias[c];
            float bn = (s - bmn[c]) * rsqrtf(bvr[c] + BN_EPS) * g[c] + be[c];
            o[j] = fmaxf(bn, 0.f);
        }
        if (FINAL) {
            float p = 0.f;
            #pragma unroll
            for (int j = 0; j < 8; ++j) p += o[j] * Wlin[sub * 8 + j];
            p += __shfl_xor(p, 1, 64);
            p += __shfl_xor(p, 2, 64);
            p += __shfl_xor(p, 4, 64);
            p += __shfl_xor(p, 8, 64);
            if (sub == 0) {
                float z = fmaxf(p + blin[0], 0.f);
                out[n] = 1.f / (1.f + __expf(-z));
            }
        } else {
            uint4 ov;
            unsigned w[4];
            #pragma unroll
            for (int q = 0; q < 4; ++q)
                w[q] = (unsigned)f2bf(o[2 * q]) | ((unsigned)f2bf(o[2 * q + 1]) << 16);
            ov.x = w[0]; ov.y = w[1]; ov.z = w[2]; ov.w = w[3];
            *(uint4*)(hout + (size_t)n * HID + sub * 8) = ov;
        }
    }

    // ---- alpha finalize ----
    // broadcast per-head (m, inv) to all lanes
    float m_h[NH], i_h[NH];
    #pragma unroll
    for (int h = 0; h < NH; ++h) {
        m_h[h] = __shfl(mrun, h * 16, 64);
        float d = __shfl(den, h * 16, 64);
        i_h[h] = 1.f / (d + 1e-16f);
    }
    if (!big) {
        // each lane finalizes all 4 heads of one edge from LDS, single 16B write
        for (int e = lane; e < deg; e += 64) {
            int eid = csr_eid[beg + e];
            float4 r = *(const float4*)&lraw[wid][e][0];
            float4 o;
            o.x = __expf(r.x - m_h[0]) * i_h[0];
            o.y = __expf(r.y - m_h[1]) * i_h[1];
            o.z = __expf(r.z - m_h[2]) * i_h[2];
            o.w = __expf(r.w - m_h[3]) * i_h[3];
            *(float4*)&alpha[(size_t)eid * NH] = o;
        }
    } else {
        // rare fallback: re-read own raw logits from global
        asm volatile("s_waitcnt vmcnt(0)" ::: "memory");
        for (int k2 = beg + sub; k2 < end; k2 += 16) {
            size_t idx = (size_t)csr_eid[k2] * NH + head;
            alpha[idx] = __expf(alpha[idx] - mrun) * inv;
        }
    }
}

extern "C" void kernel_launch(void* const* d_in, const int* in_sizes, int n_in,
                              void* d_out, int out_size, void* d_ws, size_t ws_size,
                              hipStream_t stream)
{
    const float* x    = (const float*)d_in[0];
    const int*   ei   = (const int*)d_in[1];
    const float* Wl1  = (const float*)d_in[2];
    const float* Wr1  = (const float*)d_in[3];
    const float* att1 = (const float*)d_in[4];
    const float* b1   = (const float*)d_in[5];
    const float* Wl2  = (const float*)d_in[6];
    const float* Wr2  = (const float*)d_in[7];
    const float* att2 = (const float*)d_in[8];
    const float* b2   = (const float*)d_in[9];
    const float* g1   = (const float*)d_in[10];
    const float* be1  = (const float*)d_in[11];
    const float* m1   = (const float*)d_in[12];
    const float* v1   = (const float*)d_in[13];
    const float* g2   = (const float*)d_in[14];
    const float* be2  = (const float*)d_in[15];
    const float* m2   = (const float*)d_in[16];
    const float* v2   = (const float*)d_in[17];
    const float* Wlin = (const float*)d_in[18];
    const float* blin = (const float*)d_in[19];

    const int IN_C = 256;
    const int N = in_sizes[0] / IN_C;       // 10000
    const int E = in_sizes[1] / 2;          // 320000
    const int Etot = E + N;                 // with self loops

    float* out    = (float*)d_out;          // [N]
    float* alpha1 = out + N;                // [Etot*NH]
    float* alpha2 = alpha1 + (size_t)Etot * NH;

    // workspace layout (bytes)
    char* wsb = (char*)d_ws;
    ushort* xbf   = (ushort*)wsb;                       wsb += (size_t)N * IN_C * 2;
    ushort* xlxr  = (ushort*)wsb;                       wsb += (size_t)N * F2 * 2;
    ushort* hbbf  = (ushort*)wsb;                       wsb += (size_t)N * HID * 2;
    ushort* wt1   = (ushort*)wsb;                       wsb += (size_t)F2 * IN_C * 2;  // [1024][256]
    ushort* wt2   = (ushort*)wsb;                       wsb += (size_t)F2 * HID * 2;   // [1024][128]
    int*    deg    = (int*)wsb;                         wsb += (size_t)N * 4;
    int*    cursor = (int*)wsb;                         wsb += (size_t)N * 4;
    int*    rowptr = (int*)wsb;                         wsb += (size_t)(N + 1) * 4;
    int*    csrsrc = (int*)wsb;                         wsb += (size_t)Etot * 4;
    int*    csreid = (int*)wsb;

    dim3 blk(256);
    dim3 gemm_grid((N + 127) / 128, F2 / 128);
    int node_wave_blocks = (N + 3) / 4;
    int etot_blocks = (Etot + 255) / 256;

    // ---- casts (+deg zero) ----
    cast_bf16_deg<<<(N * IN_C / 4 + 255) / 256, blk, 0, stream>>>(x, xbf, N * IN_C, deg, N);
    transpose_cast2<<<dim3(IN_C / 32, FEAT / 32, 2), blk, 0, stream>>>(Wl1, Wr1, wt1, wt1 + (size_t)FEAT * IN_C, IN_C, FEAT);
    transpose_cast2<<<dim3(HID / 32, FEAT / 32, 2), blk, 0, stream>>>(Wl2, Wr2, wt2, wt2 + (size_t)FEAT * HID, HID, FEAT);

    // ---- CSR build (shared by both layers) ----
    csr_count<<<etot_blocks, blk, 0, stream>>>(ei, deg, E, Etot);
    scan_rowptr<<<1, 1024, 0, stream>>>(deg, rowptr, cursor, N);
    csr_fill<<<etot_blocks, blk, 0, stream>>>(ei, cursor, csrsrc, csreid, E, Etot);

    // ================= layer 1 =================
    gemm_bf16<<<gemm_grid, blk, 0, stream>>>(xbf, wt1, xlxr, N, F2, IN_C);
    fused_attn<false><<<node_wave_blocks, blk, 0, stream>>>(xlxr, rowptr, csrsrc, csreid,
                                                            att1, alpha1, b1, g1, be1, m1, v1,
                                                            hbbf, Wlin, blin, out, N);

    // ================= layer 2 =================
    gemm_bf16<<<gemm_grid, blk, 0, stream>>>(hbbf, wt2, xlxr, N, F2, HID);
    fused_attn<true><<<node_wave_blocks, blk, 0, stream>>>(xlxr, rowptr, csrsrc, csreid,
                                                           att2, alpha2, b2, g2, be2, m2, v2,
                                                           hbbf, Wlin, blin, out, N);
}

// Round 12
// 209.499 us; speedup vs baseline: 1.3139x; 1.0116x over previous
//
#include <hip/hip_runtime.h>
#include <hip/hip_bf16.h>

#define HID 128
#define NH  4          // heads
#define FEAT (NH*HID)  // 512 per node per projection
#define F2   (2*FEAT)  // xl|xr packed row stride = 1024
#define NEG_SLOPE 0.2f
#define BN_EPS 1e-5f
#define CAP  128       // max buffered edges per node (deg ~ Poisson(32); fallback if exceeded)

typedef __attribute__((ext_vector_type(8))) short bf16x8;   // 8 bf16 = 4 VGPR
typedef __attribute__((ext_vector_type(4))) float f32x4;
typedef __attribute__((ext_vector_type(2))) float f32x2;

// ---------- helpers ----------
__device__ inline ushort f2bf(float f) {     // RNE f32 -> bf16
    unsigned u = __float_as_uint(f);
    return (ushort)((u + 0x7fffu + ((u >> 16) & 1u)) >> 16);
}
// unpack 8 bf16 into 4 float2 (channel pairs), pk-op friendly
__device__ inline void ubf8p(const ushort* p, f32x2* o) {
    uint4 q = *(const uint4*)p;
    o[0] = f32x2{__uint_as_float(q.x << 16), __uint_as_float(q.x & 0xffff0000u)};
    o[1] = f32x2{__uint_as_float(q.y << 16), __uint_as_float(q.y & 0xffff0000u)};
    o[2] = f32x2{__uint_as_float(q.z << 16), __uint_as_float(q.z & 0xffff0000u)};
    o[3] = f32x2{__uint_as_float(q.w << 16), __uint_as_float(q.w & 0xffff0000u)};
}

// ---------- cast f32 -> bf16 (n % 4 == 0) + zero deg ----------
__global__ __launch_bounds__(256) void cast_bf16_deg(const float* __restrict__ in,
                                                     ushort* __restrict__ out, int n,
                                                     int* __restrict__ deg, int N)
{
    int gid = blockIdx.x * 256 + threadIdx.x;
    if (gid < N) deg[gid] = 0;
    int i = gid * 4;
    if (i >= n) return;
    float4 v = *(const float4*)(in + i);
    ushort4 o = make_ushort4(f2bf(v.x), f2bf(v.y), f2bf(v.z), f2bf(v.w));
    *(ushort4*)(out + i) = o;
}

// ---------- transpose + cast four K_z x Nc f32 mats -> [Nc][K_z] bf16 ----------
__global__ __launch_bounds__(256) void transpose_cast4(const float* __restrict__ in0,
                                                       const float* __restrict__ in1,
                                                       const float* __restrict__ in2,
                                                       const float* __restrict__ in3,
                                                       ushort* __restrict__ out0,
                                                       ushort* __restrict__ out1,
                                                       ushort* __restrict__ out2,
                                                       ushort* __restrict__ out3,
                                                       int K01, int K23, int Nc)
{
    const int z = blockIdx.z;
    const float* in  = (z == 0) ? in0 : (z == 1) ? in1 : (z == 2) ? in2 : in3;
    ushort*      out = (z == 0) ? out0 : (z == 1) ? out1 : (z == 2) ? out2 : out3;
    const int K = (z < 2) ? K01 : K23;
    int bk = blockIdx.x * 32, bc = blockIdx.y * 32;
    if (bk >= K) return;
    __shared__ float t[32][33];
    int r = threadIdx.x >> 3, c4 = (threadIdx.x & 7) * 4;
    float4 v = *(const float4*)(in + (size_t)(bk + r) * Nc + bc + c4);
    t[r][c4 + 0] = v.x; t[r][c4 + 1] = v.y; t[r][c4 + 2] = v.z; t[r][c4 + 3] = v.w;
    __syncthreads();
    ushort4 o;
    o.x = f2bf(t[c4 + 0][r]); o.y = f2bf(t[c4 + 1][r]);
    o.z = f2bf(t[c4 + 2][r]); o.w = f2bf(t[c4 + 3][r]);
    *(ushort4*)(out + (size_t)(bc + r) * K + bk + c4) = o;
}

// ---------- bf16 MFMA GEMM: C[M][Nc] = A[M][K] @ Bt[Nc][K]^T ----------
// 128x128 tile, BK=32, 256 threads = 4 waves (2x2), per wave 4x4 frags 16x16.
__global__ __launch_bounds__(256) void gemm_bf16(const ushort* __restrict__ A,
                                                 const ushort* __restrict__ Bt,
                                                 ushort* __restrict__ C,
                                                 int M, int Nc, int K)
{
    __shared__ __align__(16) ushort As[128 * 40];  // row stride 40 (pad 8)
    __shared__ __align__(16) ushort Bs[128 * 40];
    const int bm = blockIdx.x * 128;
    const int bn = blockIdx.y * 128;
    const int tid = threadIdx.x;
    const int wid = tid >> 6, lane = tid & 63;
    const int wr = wid >> 1, wc = wid & 1;
    const int l15 = lane & 15, l4 = lane >> 4;

    f32x4 acc[4][4] = {};

    for (int k0 = 0; k0 < K; k0 += 32) {
        #pragma unroll
        for (int s = 0; s < 2; ++s) {               // A,B: 512 chunks of 16B each
            int c = tid + s * 256;
            int r = c >> 2, cc = (c & 3) * 8;
            uint4 v = make_uint4(0, 0, 0, 0);
            int gr = bm + r;
            if (gr < M) v = *(const uint4*)(A + (size_t)gr * K + k0 + cc);
            *(uint4*)&As[r * 40 + cc] = v;
            uint4 w = *(const uint4*)(Bt + (size_t)(bn + r) * K + k0 + cc);
            *(uint4*)&Bs[r * 40 + cc] = w;
        }
        __syncthreads();
        bf16x8 bfr[4];
        #pragma unroll
        for (int n = 0; n < 4; ++n)
            bfr[n] = *(const bf16x8*)&Bs[(wc * 64 + n * 16 + l15) * 40 + l4 * 8];
        #pragma unroll
        for (int m = 0; m < 4; ++m) {
            bf16x8 afr = *(const bf16x8*)&As[(wr * 64 + m * 16 + l15) * 40 + l4 * 8];
            #pragma unroll
            for (int n = 0; n < 4; ++n)
                acc[m][n] = __builtin_amdgcn_mfma_f32_16x16x32_bf16(afr, bfr[n], acc[m][n], 0, 0, 0);
        }
        __syncthreads();
    }
    #pragma unroll
    for (int m = 0; m < 4; ++m)
        #pragma unroll
        for (int n = 0; n < 4; ++n)
            #pragma unroll
            for (int r = 0; r < 4; ++r) {
                int row = bm + wr * 64 + m * 16 + l4 * 4 + r;
                int col = bn + wc * 64 + n * 16 + l15;
                if (row < M) C[(size_t)row * Nc + col] = f2bf(acc[m][n][r]);
            }
}

// ---------- CSR build ----------
__global__ __launch_bounds__(256) void csr_count(const int* __restrict__ ei,
                                                 int* __restrict__ deg,
                                                 int E, int Etot)
{
    int i = blockIdx.x * 256 + threadIdx.x;
    if (i >= Etot) return;
    int dst = (i < E) ? ei[E + i] : (i - E);
    atomicAdd(&deg[dst], 1);
}

__global__ __launch_bounds__(1024) void scan_rowptr(const int* __restrict__ deg,
                                                    int* __restrict__ rowptr,
                                                    int* __restrict__ cursor,
                                                    int N)
{
    __shared__ int part[1024];
    int t = threadIdx.x;
    int chunk = (N + 1023) / 1024;
    int lo = t * chunk;
    int hi = lo + chunk; if (hi > N) hi = N; if (lo > N) lo = N;
    int s = 0;
    for (int i = lo; i < hi; ++i) s += deg[i];
    part[t] = s;
    __syncthreads();
    for (int off = 1; off < 1024; off <<= 1) {
        int v = (t >= off) ? part[t - off] : 0;
        __syncthreads();
        part[t] += v;
        __syncthreads();
    }
    int base = (t == 0) ? 0 : part[t - 1];
    for (int i = lo; i < hi; ++i) {
        rowptr[i] = base;
        cursor[i] = base;
        base += deg[i];
    }
    if (t == 1023) rowptr[N] = part[1023];
}

__global__ __launch_bounds__(256) void csr_fill(const int* __restrict__ ei,
                                                int* __restrict__ cursor,
                                                int* __restrict__ csr_src,
                                                int* __restrict__ csr_eid,
                                                int E, int Etot)
{
    int i = blockIdx.x * 256 + threadIdx.x;
    if (i >= Etot) return;
    int src, dst;
    if (i < E) { src = ei[i]; dst = ei[E + i]; }
    else       { src = dst = i - E; }
    int pos = atomicAdd(&cursor[dst], 1);
    csr_src[pos] = src;
    csr_eid[pos] = i;
}

// ---------- fused per-dst attention (unroll-4, LDS logit buffer, packed-f32 math) ----------
// One wave per node; head = lane>>4, sub = lane&15 covers 8 channels (16B/lane).
// Inner math on float2 channel pairs -> v_pk_{add,mul,fma}_f32.
// FINAL=false: write h (bf16). FINAL=true: fuse h@Wlin+blin -> relu -> sigmoid.
template <bool FINAL>
__global__ __launch_bounds__(256) void fused_attn(const ushort* __restrict__ xlxr,
                                                  const int* __restrict__ rowptr,
                                                  const int* __restrict__ csr_src,
                                                  const int* __restrict__ csr_eid,
                                                  const float* __restrict__ att,
                                                  float* __restrict__ alpha,
                                                  const float* __restrict__ bias,
                                                  const float* __restrict__ g,
                                                  const float* __restrict__ be,
                                                  const float* __restrict__ bmn,
                                                  const float* __restrict__ bvr,
                                                  ushort* __restrict__ hout,
                                                  const float* __restrict__ Wlin,
                                                  const float* __restrict__ blin,
                                                  float* __restrict__ out, int N)
{
    __shared__ __align__(16) float lraw[4][CAP][NH];   // 8 KB, wave-local
    int n = (blockIdx.x * 256 + threadIdx.x) >> 6;
    int lane = threadIdx.x & 63;
    if (n >= N) return;
    const int wid = (threadIdx.x >> 6);
    int head = lane >> 4, sub = lane & 15;
    const size_t foff = (size_t)head * HID + sub * 8;

    f32x2 xr2[4], at2[4];
    ubf8p(xlxr + (size_t)n * F2 + FEAT + foff, xr2);
    {
        const float4* a4 = (const float4*)(att + foff);
        float4 t0 = a4[0], t1 = a4[1];
        at2[0] = f32x2{t0.x, t0.y}; at2[1] = f32x2{t0.z, t0.w};
        at2[2] = f32x2{t1.x, t1.y}; at2[3] = f32x2{t1.z, t1.w};
    }

    float mrun = -1e30f, den = 0.f;
    f32x2 acc2[4] = {};
    const int beg = rowptr[n], end = rowptr[n + 1];
    const int deg = end - beg;
    const bool big = deg > CAP;       // wave-uniform
    int k = beg;

    for (; k + 3 < end; k += 4) {
        int s0 = csr_src[k],     s1 = csr_src[k + 1];
        int s2 = csr_src[k + 2], s3 = csr_src[k + 3];

        f32x2 xv0[4], xv1[4], xv2[4], xv3[4];
        ubf8p(xlxr + (size_t)s0 * F2 + foff, xv0);
        ubf8p(xlxr + (size_t)s1 * F2 + foff, xv1);
        ubf8p(xlxr + (size_t)s2 * F2 + foff, xv2);
        ubf8p(xlxr + (size_t)s3 * F2 + foff, xv3);

        f32x2 p0 = {}, p1 = {}, p2 = {}, p3 = {};
        #pragma unroll
        for (int j = 0; j < 4; ++j) {
            f32x2 t0 = xv0[j] + xr2[j];
            f32x2 t1 = xv1[j] + xr2[j];
            f32x2 t2 = xv2[j] + xr2[j];
            f32x2 t3 = xv3[j] + xr2[j];
            f32x2 u0 = t0 * NEG_SLOPE, u1 = t1 * NEG_SLOPE;
            f32x2 u2 = t2 * NEG_SLOPE, u3 = t3 * NEG_SLOPE;
            t0.x = fmaxf(t0.x, u0.x); t0.y = fmaxf(t0.y, u0.y);
            t1.x = fmaxf(t1.x, u1.x); t1.y = fmaxf(t1.y, u1.y);
            t2.x = fmaxf(t2.x, u2.x); t2.y = fmaxf(t2.y, u2.y);
            t3.x = fmaxf(t3.x, u3.x); t3.y = fmaxf(t3.y, u3.y);
            p0 += t0 * at2[j]; p1 += t1 * at2[j];
            p2 += t2 * at2[j]; p3 += t3 * at2[j];
        }
        float l0 = p0.x + p0.y, l1 = p1.x + p1.y;
        float l2 = p2.x + p2.y, l3 = p3.x + p3.y;
        #pragma unroll
        for (int off = 1; off < 16; off <<= 1) {
            l0 += __shfl_xor(l0, off, 64);
            l1 += __shfl_xor(l1, off, 64);
            l2 += __shfl_xor(l2, off, 64);
            l3 += __shfl_xor(l3, off, 64);
        }
        if (!big) {
            if (sub == 0) {
                int kk = k - beg;
                lraw[wid][kk + 0][head] = l0;
                lraw[wid][kk + 1][head] = l1;
                lraw[wid][kk + 2][head] = l2;
                lraw[wid][kk + 3][head] = l3;
            }
        } else if (sub == 0) {
            alpha[(size_t)csr_eid[k]     * NH + head] = l0;
            alpha[(size_t)csr_eid[k + 1] * NH + head] = l1;
            alpha[(size_t)csr_eid[k + 2] * NH + head] = l2;
            alpha[(size_t)csr_eid[k + 3] * NH + head] = l3;
        }
        float bmax = fmaxf(fmaxf(l0, l1), fmaxf(l2, l3));
        if (bmax > mrun) {
            float sc = __expf(mrun - bmax);
            den *= sc;
            #pragma unroll
            for (int j = 0; j < 4; ++j) acc2[j] *= sc;
            mrun = bmax;
        }
        float w0 = __expf(l0 - mrun), w1 = __expf(l1 - mrun);
        float w2 = __expf(l2 - mrun), w3 = __expf(l3 - mrun);
        den += (w0 + w1) + (w2 + w3);
        #pragma unroll
        for (int j = 0; j < 4; ++j)
            acc2[j] += (w0 * xv0[j] + w1 * xv1[j]) + (w2 * xv2[j] + w3 * xv3[j]);
    }

    for (; k < end; ++k) {
        int src = csr_src[k];
        f32x2 xv[4];
        ubf8p(xlxr + (size_t)src * F2 + foff, xv);
        f32x2 ps = {};
        #pragma unroll
        for (int j = 0; j < 4; ++j) {
            f32x2 t = xv[j] + xr2[j];
            f32x2 u = t * NEG_SLOPE;
            t.x = fmaxf(t.x, u.x); t.y = fmaxf(t.y, u.y);
            ps += t * at2[j];
        }
        float s = ps.x + ps.y;
        #pragma unroll
        for (int off = 1; off < 16; off <<= 1) s += __shfl_xor(s, off, 64);
        if (!big) {
            if (sub == 0) lraw[wid][k - beg][head] = s;
        } else if (sub == 0) {
            alpha[(size_t)csr_eid[k] * NH + head] = s;
        }
        if (s > mrun) {
            float sc = __expf(mrun - s);
            den *= sc;
            #pragma unroll
            for (int j = 0; j < 4; ++j) acc2[j] *= sc;
            mrun = s;
        }
        float e = __expf(s - mrun);
        den += e;
        #pragma unroll
        for (int j = 0; j < 4; ++j) acc2[j] += e * xv[j];
    }

    float inv = 1.f / (den + 1e-16f);

    // head-mean via cross-head shuffles
    float t8[8];
    #pragma unroll
    for (int j = 0; j < 4; ++j) {
        float ta = acc2[j].x * inv;
        float tb = acc2[j].y * inv;
        ta += __shfl_xor(ta, 16, 64);
        ta += __shfl_xor(ta, 32, 64);
        tb += __shfl_xor(tb, 16, 64);
        tb += __shfl_xor(tb, 32, 64);
        t8[2 * j] = ta; t8[2 * j + 1] = tb;
    }
    if (head == 0) {
        float o[8];
        #pragma unroll
        for (int j = 0; j < 8; ++j) {
            int c = sub * 8 + j;
            float s = t8[j] * 0.25f + bias[c];
            float bn = (s - bmn[c]) * rsqrtf(bvr[c] + BN_EPS) * g[c] + be[c];
            o[j] = fmaxf(bn, 0.f);
        }
        if (FINAL) {
            float p = 0.f;
            #pragma unroll
            for (int j = 0; j < 8; ++j) p += o[j] * Wlin[sub * 8 + j];
            p += __shfl_xor(p, 1, 64);
            p += __shfl_xor(p, 2, 64);
            p += __shfl_xor(p, 4, 64);
            p += __shfl_xor(p, 8, 64);
            if (sub == 0) {
                float z = fmaxf(p + blin[0], 0.f);
                out[n] = 1.f / (1.f + __expf(-z));
            }
        } else {
            uint4 ov;
            unsigned w[4];
            #pragma unroll
            for (int q = 0; q < 4; ++q)
                w[q] = (unsigned)f2bf(o[2 * q]) | ((unsigned)f2bf(o[2 * q + 1]) << 16);
            ov.x = w[0]; ov.y = w[1]; ov.z = w[2]; ov.w = w[3];
            *(uint4*)(hout + (size_t)n * HID + sub * 8) = ov;
        }
    }

    // ---- alpha finalize ----
    float m_h[NH], i_h[NH];
    #pragma unroll
    for (int h = 0; h < NH; ++h) {
        m_h[h] = __shfl(mrun, h * 16, 64);
        float d = __shfl(den, h * 16, 64);
        i_h[h] = 1.f / (d + 1e-16f);
    }
    if (!big) {
        // each lane finalizes all 4 heads of one edge from LDS, single 16B write
        for (int e = lane; e < deg; e += 64) {
            int eid = csr_eid[beg + e];
            float4 r = *(const float4*)&lraw[wid][e][0];
            float4 o;
            o.x = __expf(r.x - m_h[0]) * i_h[0];
            o.y = __expf(r.y - m_h[1]) * i_h[1];
            o.z = __expf(r.z - m_h[2]) * i_h[2];
            o.w = __expf(r.w - m_h[3]) * i_h[3];
            *(float4*)&alpha[(size_t)eid * NH] = o;
        }
    } else {
        // rare fallback: re-read own raw logits from global
        asm volatile("s_waitcnt vmcnt(0)" ::: "memory");
        float minv = i_h[head];
        for (int k2 = beg + sub; k2 < end; k2 += 16) {
            size_t idx = (size_t)csr_eid[k2] * NH + head;
            alpha[idx] = __expf(alpha[idx] - m_h[head]) * minv;
        }
    }
}

extern "C" void kernel_launch(void* const* d_in, const int* in_sizes, int n_in,
                              void* d_out, int out_size, void* d_ws, size_t ws_size,
                              hipStream_t stream)
{
    const float* x    = (const float*)d_in[0];
    const int*   ei   = (const int*)d_in[1];
    const float* Wl1  = (const float*)d_in[2];
    const float* Wr1  = (const float*)d_in[3];
    const float* att1 = (const float*)d_in[4];
    const float* b1   = (const float*)d_in[5];
    const float* Wl2  = (const float*)d_in[6];
    const float* Wr2  = (const float*)d_in[7];
    const float* att2 = (const float*)d_in[8];
    const float* b2   = (const float*)d_in[9];
    const float* g1   = (const float*)d_in[10];
    const float* be1  = (const float*)d_in[11];
    const float* m1   = (const float*)d_in[12];
    const float* v1   = (const float*)d_in[13];
    const float* g2   = (const float*)d_in[14];
    const float* be2  = (const float*)d_in[15];
    const float* m2   = (const float*)d_in[16];
    const float* v2   = (const float*)d_in[17];
    const float* Wlin = (const float*)d_in[18];
    const float* blin = (const float*)d_in[19];

    const int IN_C = 256;
    const int N = in_sizes[0] / IN_C;       // 10000
    const int E = in_sizes[1] / 2;          // 320000
    const int Etot = E + N;                 // with self loops

    float* out    = (float*)d_out;          // [N]
    float* alpha1 = out + N;                // [Etot*NH]
    float* alpha2 = alpha1 + (size_t)Etot * NH;

    // workspace layout (bytes)
    char* wsb = (char*)d_ws;
    ushort* xbf   = (ushort*)wsb;                       wsb += (size_t)N * IN_C * 2;
    ushort* xlxr  = (ushort*)wsb;                       wsb += (size_t)N * F2 * 2;
    ushort* hbbf  = (ushort*)wsb;                       wsb += (size_t)N * HID * 2;
    ushort* wt1   = (ushort*)wsb;                       wsb += (size_t)F2 * IN_C * 2;  // [1024][256]
    ushort* wt2   = (ushort*)wsb;                       wsb += (size_t)F2 * HID * 2;   // [1024][128]
    int*    deg    = (int*)wsb;                         wsb += (size_t)N * 4;
    int*    cursor = (int*)wsb;                         wsb += (size_t)N * 4;
    int*    rowptr = (int*)wsb;                         wsb += (size_t)(N + 1) * 4;
    int*    csrsrc = (int*)wsb;                         wsb += (size_t)Etot * 4;
    int*    csreid = (int*)wsb;

    dim3 blk(256);
    dim3 gemm_grid((N + 127) / 128, F2 / 128);
    int node_wave_blocks = (N + 3) / 4;
    int etot_blocks = (Etot + 255) / 256;

    // ---- casts (+deg zero) ----
    cast_bf16_deg<<<(N * IN_C / 4 + 255) / 256, blk, 0, stream>>>(x, xbf, N * IN_C, deg, N);
    transpose_cast4<<<dim3(IN_C / 32, FEAT / 32, 4), blk, 0, stream>>>(
        Wl1, Wr1, Wl2, Wr2,
        wt1, wt1 + (size_t)FEAT * IN_C, wt2, wt2 + (size_t)FEAT * HID,
        IN_C, HID, FEAT);

    // ---- CSR build (shared by both layers) ----
    csr_count<<<etot_blocks, blk, 0, stream>>>(ei, deg, E, Etot);
    scan_rowptr<<<1, 1024, 0, stream>>>(deg, rowptr, cursor, N);
    csr_fill<<<etot_blocks, blk, 0, stream>>>(ei, cursor, csrsrc, csreid, E, Etot);

    // ================= layer 1 =================
    gemm_bf16<<<gemm_grid, blk, 0, stream>>>(xbf, wt1, xlxr, N, F2, IN_C);
    fused_attn<false><<<node_wave_blocks, blk, 0, stream>>>(xlxr, rowptr, csrsrc, csreid,
                                                            att1, alpha1, b1, g1, be1, m1, v1,
                                                            hbbf, Wlin, blin, out, N);

    // ================= layer 2 =================
    gemm_bf16<<<gemm_grid, blk, 0, stream>>>(hbbf, wt2, xlxr, N, F2, HID);
    fused_attn<true><<<node_wave_blocks, blk, 0, stream>>>(xlxr, rowptr, csrsrc, csreid,
                                                           att2, alpha2, b2, g2, be2, m2, v2,
                                                           hbbf, Wlin, blin, out, N);
}